// Round 1
// baseline (1080.902 us; speedup 1.0000x reference)
//
#include <hip/hip_runtime.h>
#include <hip/hip_bf16.h>

// 3-layer GCN: h = A_norm * (x @ W) + b per layer, relu between.
// A_norm = D^-1/2 (A + I) D^-1/2, deg = in-degree + 1 (self loop).
// Strategy: fold dinv into GEMM epilogue (s = (x@W)*dinv[row]); then
// out[i] = dinv[i]*(sum_{src->i} s[src] + s[i]) + b  via CSR gather (no f32 atomics).

#define WAVE 64

// ---------------- CSR build ----------------

__global__ void k_count(const int* __restrict__ dst, int* __restrict__ cnt, int E) {
    int e = blockIdx.x * blockDim.x + threadIdx.x;
    if (e < E) atomicAdd(&cnt[dst[e]], 1);
}

__global__ void k_dinv(const int* __restrict__ cnt, float* __restrict__ dinv, int N) {
    int i = blockIdx.x * blockDim.x + threadIdx.x;
    if (i < N) dinv[i] = rsqrtf((float)cnt[i] + 1.0f);
}

// Block-level Hillis-Steele scan: excl[g] = exclusive-within-block, bsum[b] = block total
__global__ void k_scan1(const int* __restrict__ cnt, int* __restrict__ excl,
                        int* __restrict__ bsum, int N) {
    __shared__ int tmp[256];
    int t = threadIdx.x;
    int g = blockIdx.x * 256 + t;
    int v = (g < N) ? cnt[g] : 0;
    tmp[t] = v;
    __syncthreads();
    for (int off = 1; off < 256; off <<= 1) {
        int add = (t >= off) ? tmp[t - off] : 0;
        __syncthreads();
        tmp[t] += add;
        __syncthreads();
    }
    int incl = tmp[t];
    if (g < N) excl[g] = incl - v;
    if (t == 255) bsum[blockIdx.x] = incl;
}

// Single-block exclusive scan of block sums (NB <= 512)
__global__ void k_scan2(int* __restrict__ bsum, int NB) {
    __shared__ int tmp[512];
    int t = threadIdx.x;
    int v = (t < NB) ? bsum[t] : 0;
    tmp[t] = v;
    __syncthreads();
    for (int off = 1; off < 512; off <<= 1) {
        int add = (t >= off) ? tmp[t - off] : 0;
        __syncthreads();
        tmp[t] += add;
        __syncthreads();
    }
    if (t < NB) bsum[t] = tmp[t] - v;  // exclusive
}

__global__ void k_scan3(int* __restrict__ excl, const int* __restrict__ bsum,
                        int* __restrict__ cursor, int N) {
    int g = blockIdx.x * 256 + threadIdx.x;
    if (g < N) {
        int v = excl[g] + bsum[blockIdx.x];
        excl[g] = v;     // row_start
        cursor[g] = v;   // fill cursor
    }
}

__global__ void k_fill(const int* __restrict__ src, const int* __restrict__ dst,
                       int* __restrict__ cursor, int* __restrict__ ssorted, int E) {
    int e = blockIdx.x * blockDim.x + threadIdx.x;
    if (e < E) {
        int p = atomicAdd(&cursor[dst[e]], 1);
        ssorted[p] = src[e];
    }
}

// ---------------- Dense GEMM: out[row, c0:c0+M/CS] = (A[row,:] @ W) * dinv[row] ----------------
// Thread-per-row; W reads are wave-uniform -> scalarized (s_load), 1 VALU FMA per MAC.

template <int K, int M, int CS>
__global__ __launch_bounds__(256) void gemm_rows(const float* __restrict__ A,
                                                 const float* __restrict__ W,
                                                 const float* __restrict__ rowscale,
                                                 float* __restrict__ out, int N) {
    constexpr int MC = M / CS;
    int row = blockIdx.x * blockDim.x + threadIdx.x;
    int c0 = blockIdx.y * MC;
    if (row >= N) return;
    float acc[MC];
#pragma unroll
    for (int j = 0; j < MC; ++j) acc[j] = 0.f;
    const float* a = A + (size_t)row * K;
    for (int k = 0; k < K; k += 4) {
        float4 av = *reinterpret_cast<const float4*>(a + k);
        const float avs[4] = {av.x, av.y, av.z, av.w};
#pragma unroll
        for (int kk = 0; kk < 4; ++kk) {
            const float* wrow = W + (size_t)(k + kk) * M + c0;  // wave-uniform address
#pragma unroll
            for (int j = 0; j < MC; ++j) acc[j] += avs[kk] * wrow[j];
        }
    }
    float sc = rowscale[row];
    float* o = out + (size_t)row * M + c0;
#pragma unroll
    for (int j = 0; j < MC; ++j) o[j] = acc[j] * sc;
}

// ---------------- CSR aggregation: one wave per node ----------------
// out[i,:] = act( dinv[i] * (sum_{e in row i} S[src_e,:] + S[i,:]) + bias )

template <int M, bool RELU>
__global__ __launch_bounds__(256) void agg_csr(const float* __restrict__ S,
                                               const int* __restrict__ ssorted,
                                               const int* __restrict__ rstart,
                                               const int* __restrict__ cnt,
                                               const float* __restrict__ dinv,
                                               const float* __restrict__ bias,
                                               float* __restrict__ out, int N) {
    constexpr int L = (M + WAVE - 1) / WAVE;
    int wid = (blockIdx.x * blockDim.x + threadIdx.x) >> 6;
    int lane = threadIdx.x & 63;
    if (wid >= N) return;
    int start = rstart[wid];
    int c = cnt[wid];
    float acc[L];
#pragma unroll
    for (int l = 0; l < L; ++l) {
        int col = lane + WAVE * l;
        acc[l] = (col < M) ? S[(size_t)wid * M + col] : 0.f;  // self loop
    }
    for (int e = 0; e < c; ++e) {
        int s = ssorted[start + e];  // wave-uniform -> s_load
#pragma unroll
        for (int l = 0; l < L; ++l) {
            int col = lane + WAVE * l;
            if (col < M) acc[l] += S[(size_t)s * M + col];
        }
    }
    float di = dinv[wid];
#pragma unroll
    for (int l = 0; l < L; ++l) {
        int col = lane + WAVE * l;
        if (col < M) {
            float v = acc[l] * di + bias[col];
            if (RELU) v = fmaxf(v, 0.f);
            out[(size_t)wid * M + col] = v;
        }
    }
}

// ---------------- launch ----------------

extern "C" void kernel_launch(void* const* d_in, const int* in_sizes, int n_in,
                              void* d_out, int out_size, void* d_ws, size_t ws_size,
                              hipStream_t stream) {
    const float* x  = (const float*)d_in[0];
    const int*   ei = (const int*)d_in[1];
    const float* W1 = (const float*)d_in[2];
    const float* b1 = (const float*)d_in[3];
    const float* W2 = (const float*)d_in[4];
    const float* b2 = (const float*)d_in[5];
    const float* W3 = (const float*)d_in[6];
    const float* b3 = (const float*)d_in[7];
    float* out = (float*)d_out;

    const int IN_DIM = 256, HID = 128, NCLS = 40;
    const int N = in_sizes[0] / IN_DIM;
    const int E = in_sizes[1] / 2;
    const int* srcE = ei;
    const int* dstE = ei + E;

    char* ws = (char*)d_ws;
    size_t off = 0;
    auto alloc = [&](size_t bytes) -> void* {
        off = (off + 255) & ~(size_t)255;
        void* p = ws + off;
        off += bytes;
        return p;
    };
    int*   cnt     = (int*)alloc((size_t)N * 4);
    int*   rstart  = (int*)alloc((size_t)N * 4);
    int*   cursor  = (int*)alloc((size_t)N * 4);
    int*   bsum    = (int*)alloc(512 * 4);
    float* dinv    = (float*)alloc((size_t)N * 4);
    int*   ssorted = (int*)alloc((size_t)E * 4);
    float* bufS    = (float*)alloc((size_t)N * HID * 4);
    float* bufH    = (float*)alloc((size_t)N * HID * 4);

    const int NB = (N + 255) / 256;       // 391
    const int EB = (E + 255) / 256;       // 6250
    const int AGGB = (N * WAVE + 255) / 256;  // 25000 blocks (wave per node)

    // CSR build + dinv
    hipMemsetAsync(cnt, 0, (size_t)N * 4, stream);
    k_count<<<EB, 256, 0, stream>>>(dstE, cnt, E);
    k_dinv<<<NB, 256, 0, stream>>>(cnt, dinv, N);
    k_scan1<<<NB, 256, 0, stream>>>(cnt, rstart, bsum, N);
    k_scan2<<<1, 512, 0, stream>>>(bsum, NB);
    k_scan3<<<NB, 256, 0, stream>>>(rstart, bsum, cursor, N);
    k_fill<<<EB, 256, 0, stream>>>(srcE, dstE, cursor, ssorted, E);

    // Layer 1: 256 -> 128, relu
    {
        dim3 g(NB, 2);
        gemm_rows<256, 128, 2><<<g, 256, 0, stream>>>(x, W1, dinv, bufS, N);
        agg_csr<128, true><<<AGGB, 256, 0, stream>>>(bufS, ssorted, rstart, cnt, dinv, b1, bufH, N);
    }
    // Layer 2: 128 -> 128, relu
    {
        dim3 g(NB, 2);
        gemm_rows<128, 128, 2><<<g, 256, 0, stream>>>(bufH, W2, dinv, bufS, N);
        agg_csr<128, true><<<AGGB, 256, 0, stream>>>(bufS, ssorted, rstart, cnt, dinv, b2, bufH, N);
    }
    // Layer 3: 128 -> 40, no relu, straight to d_out
    {
        dim3 g(NB, 1);
        gemm_rows<128, 40, 1><<<g, 256, 0, stream>>>(bufH, W3, dinv, bufS, N);
        agg_csr<40, false><<<AGGB, 256, 0, stream>>>(bufS, ssorted, rstart, cnt, dinv, b3, out, N);
    }
}

// Round 2
// 839.430 us; speedup vs baseline: 1.2877x; 1.2877x over previous
//
#include <hip/hip_runtime.h>
#include <hip/hip_bf16.h>

// 3-layer GCN: h = A_norm * (x @ W) + b per layer, relu between.
// A_norm = D^-1/2 (A + I) D^-1/2, deg = in-degree + 1 (self loop).
// s = (x@W)*dinv[row] in GEMM epilogue; out[i] = dinv[i]*(sum s[src] + s[i]) + b via CSR.

#define WAVE 64

// ---------------- CSR build ----------------

__global__ void k_count(const int* __restrict__ dst, int* __restrict__ cnt, int E) {
    int e = blockIdx.x * blockDim.x + threadIdx.x;
    if (e < E) atomicAdd(&cnt[dst[e]], 1);
}

__global__ void k_dinv(const int* __restrict__ cnt, float* __restrict__ dinv, int N) {
    int i = blockIdx.x * blockDim.x + threadIdx.x;
    if (i < N) dinv[i] = rsqrtf((float)cnt[i] + 1.0f);
}

__global__ void k_scan1(const int* __restrict__ cnt, int* __restrict__ excl,
                        int* __restrict__ bsum, int N) {
    __shared__ int tmp[256];
    int t = threadIdx.x;
    int g = blockIdx.x * 256 + t;
    int v = (g < N) ? cnt[g] : 0;
    tmp[t] = v;
    __syncthreads();
    for (int off = 1; off < 256; off <<= 1) {
        int add = (t >= off) ? tmp[t - off] : 0;
        __syncthreads();
        tmp[t] += add;
        __syncthreads();
    }
    int incl = tmp[t];
    if (g < N) excl[g] = incl - v;
    if (t == 255) bsum[blockIdx.x] = incl;
}

__global__ void k_scan2(int* __restrict__ bsum, int NB) {
    __shared__ int tmp[512];
    int t = threadIdx.x;
    int v = (t < NB) ? bsum[t] : 0;
    tmp[t] = v;
    __syncthreads();
    for (int off = 1; off < 512; off <<= 1) {
        int add = (t >= off) ? tmp[t - off] : 0;
        __syncthreads();
        tmp[t] += add;
        __syncthreads();
    }
    if (t < NB) bsum[t] = tmp[t] - v;
}

__global__ void k_scan3(int* __restrict__ excl, const int* __restrict__ bsum,
                        int* __restrict__ cursor, int N) {
    int g = blockIdx.x * 256 + threadIdx.x;
    if (g < N) {
        int v = excl[g] + bsum[blockIdx.x];
        excl[g] = v;
        cursor[g] = v;
    }
}

__global__ void k_fill(const int* __restrict__ src, const int* __restrict__ dst,
                       int* __restrict__ cursor, int* __restrict__ ssorted, int E) {
    int e = blockIdx.x * blockDim.x + threadIdx.x;
    if (e < E) {
        int p = atomicAdd(&cursor[dst[e]], 1);
        ssorted[p] = src[e];
    }
}

// ---------------- LDS-tiled SGEMM: out[r, :] = (A[r,:] @ W) * dinv[r] ----------------
// Block: 256 threads = TY x TX, tile TM=TY*MR rows x M cols, micro-tile MR x MC2.
// A staged coalesced into LDS (transposed, padded); W chunk staged row-major.

template <int K, int M, int TX, int TY, int MR, int MC2>
__global__ __launch_bounds__(256) void gemm_tile(const float* __restrict__ A,
                                                 const float* __restrict__ W,
                                                 const float* __restrict__ rowscale,
                                                 float* __restrict__ out, int N) {
    constexpr int KC = 16;
    constexpr int TM = TY * MR;       // 128
    constexpr int TMP = TM + 4;       // pad: staging writes land 2-way (free), not 4-way
    static_assert(TX * TY == 256 && TX * MC2 == M && TM == 128, "cfg");
    __shared__ float As[KC * TMP];    // As[k][row]
    __shared__ float Ws[KC * M];      // Ws[k][col]

    const int tid = threadIdx.x;
    const int tx = tid % TX, ty = tid / TX;
    const int r0 = blockIdx.x * TM;

    float acc[MR][MC2];
#pragma unroll
    for (int i = 0; i < MR; ++i)
#pragma unroll
        for (int j = 0; j < MC2; ++j) acc[i][j] = 0.f;

    for (int kc = 0; kc < K; kc += KC) {
        // stage A tile: TM rows x KC k, float4 per thread-iter, coalesced 64B segments
        constexpr int F4R = KC / 4;   // float4 per row = 4
        for (int f = tid; f < TM * F4R; f += 256) {
            int row = f / F4R, kq = f % F4R;
            int grow = r0 + row;
            if (grow > N - 1) grow = N - 1;  // clamp; garbage rows never stored
            float4 v = *reinterpret_cast<const float4*>(A + (size_t)grow * K + kc + kq * 4);
            As[(kq * 4 + 0) * TMP + row] = v.x;
            As[(kq * 4 + 1) * TMP + row] = v.y;
            As[(kq * 4 + 2) * TMP + row] = v.z;
            As[(kq * 4 + 3) * TMP + row] = v.w;
        }
        // stage W chunk: KC x M
        constexpr int WF4 = KC * M / 4;
        for (int f = tid; f < WF4; f += 256) {
            int k = f / (M / 4), cq = f % (M / 4);
            *reinterpret_cast<float4*>(&Ws[k * M + cq * 4]) =
                *reinterpret_cast<const float4*>(W + (size_t)(kc + k) * M + cq * 4);
        }
        __syncthreads();
#pragma unroll
        for (int k = 0; k < KC; ++k) {
            float a[MR], b[MC2];
#pragma unroll
            for (int i = 0; i < MR; ++i) a[i] = As[k * TMP + ty * MR + i];  // bcast across tx
#pragma unroll
            for (int j = 0; j < MC2; ++j) b[j] = Ws[k * M + tx * MC2 + j];  // bcast across ty
#pragma unroll
            for (int i = 0; i < MR; ++i)
#pragma unroll
                for (int j = 0; j < MC2; ++j) acc[i][j] += a[i] * b[j];
        }
        __syncthreads();
    }

#pragma unroll
    for (int i = 0; i < MR; ++i) {
        int r = r0 + ty * MR + i;
        if (r < N) {
            float sc = rowscale[r];
            float* o = out + (size_t)r * M + tx * MC2;
#pragma unroll
            for (int j = 0; j < MC2; ++j) o[j] = acc[i][j] * sc;
        }
    }
}

// ---------------- CSR aggregation ----------------
// M=128: wave per node, float2 per lane, 4-wide edge unroll for MLP.

template <bool RELU>
__global__ __launch_bounds__(256) void agg128(const float* __restrict__ S,
                                              const int* __restrict__ ssorted,
                                              const int* __restrict__ rstart,
                                              const int* __restrict__ cnt,
                                              const float* __restrict__ dinv,
                                              const float* __restrict__ bias,
                                              float* __restrict__ out, int N) {
    int wid = (blockIdx.x * blockDim.x + threadIdx.x) >> 6;
    int lane = threadIdx.x & 63;
    if (wid >= N) return;
    const float2* S2 = (const float2*)S;
    int start = rstart[wid];
    int c = cnt[wid];
    float2 a = S2[(size_t)wid * 64 + lane];  // self loop
    float ax = a.x, ay = a.y;
    int e = 0;
    for (; e + 4 <= c; e += 4) {
        int s0 = ssorted[start + e + 0];
        int s1 = ssorted[start + e + 1];
        int s2 = ssorted[start + e + 2];
        int s3 = ssorted[start + e + 3];
        float2 v0 = S2[(size_t)s0 * 64 + lane];
        float2 v1 = S2[(size_t)s1 * 64 + lane];
        float2 v2 = S2[(size_t)s2 * 64 + lane];
        float2 v3 = S2[(size_t)s3 * 64 + lane];
        ax += v0.x + v1.x + v2.x + v3.x;
        ay += v0.y + v1.y + v2.y + v3.y;
    }
    for (; e < c; ++e) {
        int s = ssorted[start + e];
        float2 v = S2[(size_t)s * 64 + lane];
        ax += v.x;
        ay += v.y;
    }
    float di = dinv[wid];
    float2 bv = ((const float2*)bias)[lane];
    float ox = ax * di + bv.x;
    float oy = ay * di + bv.y;
    if (RELU) { ox = fmaxf(ox, 0.f); oy = fmaxf(oy, 0.f); }
    float2 o = make_float2(ox, oy);
    ((float2*)out)[(size_t)wid * 64 + lane] = o;
}

// M=40: wave per node, scalar per lane (lanes 0..39), 4-wide edge unroll.
__global__ __launch_bounds__(256) void agg40(const float* __restrict__ S,
                                             const int* __restrict__ ssorted,
                                             const int* __restrict__ rstart,
                                             const int* __restrict__ cnt,
                                             const float* __restrict__ dinv,
                                             const float* __restrict__ bias,
                                             float* __restrict__ out, int N) {
    int wid = (blockIdx.x * blockDim.x + threadIdx.x) >> 6;
    int lane = threadIdx.x & 63;
    if (wid >= N || lane >= 40) return;
    int start = rstart[wid];
    int c = cnt[wid];
    float acc = S[(size_t)wid * 40 + lane];
    int e = 0;
    for (; e + 4 <= c; e += 4) {
        int s0 = ssorted[start + e + 0];
        int s1 = ssorted[start + e + 1];
        int s2 = ssorted[start + e + 2];
        int s3 = ssorted[start + e + 3];
        float v0 = S[(size_t)s0 * 40 + lane];
        float v1 = S[(size_t)s1 * 40 + lane];
        float v2 = S[(size_t)s2 * 40 + lane];
        float v3 = S[(size_t)s3 * 40 + lane];
        acc += v0 + v1 + v2 + v3;
    }
    for (; e < c; ++e) {
        int s = ssorted[start + e];
        acc += S[(size_t)s * 40 + lane];
    }
    out[(size_t)wid * 40 + lane] = acc * dinv[wid] + bias[lane];
}

// ---------------- launch ----------------

extern "C" void kernel_launch(void* const* d_in, const int* in_sizes, int n_in,
                              void* d_out, int out_size, void* d_ws, size_t ws_size,
                              hipStream_t stream) {
    const float* x  = (const float*)d_in[0];
    const int*   ei = (const int*)d_in[1];
    const float* W1 = (const float*)d_in[2];
    const float* b1 = (const float*)d_in[3];
    const float* W2 = (const float*)d_in[4];
    const float* b2 = (const float*)d_in[5];
    const float* W3 = (const float*)d_in[6];
    const float* b3 = (const float*)d_in[7];
    float* out = (float*)d_out;

    const int IN_DIM = 256, HID = 128;
    const int N = in_sizes[0] / IN_DIM;
    const int E = in_sizes[1] / 2;
    const int* srcE = ei;
    const int* dstE = ei + E;

    char* ws = (char*)d_ws;
    size_t off = 0;
    auto alloc = [&](size_t bytes) -> void* {
        off = (off + 255) & ~(size_t)255;
        void* p = ws + off;
        off += bytes;
        return p;
    };
    int*   cnt     = (int*)alloc((size_t)N * 4);
    int*   rstart  = (int*)alloc((size_t)N * 4);
    int*   cursor  = (int*)alloc((size_t)N * 4);
    int*   bsum    = (int*)alloc(512 * 4);
    float* dinv    = (float*)alloc((size_t)N * 4);
    int*   ssorted = (int*)alloc((size_t)E * 4);
    float* bufS    = (float*)alloc((size_t)N * HID * 4);
    float* bufH    = (float*)alloc((size_t)N * HID * 4);

    const int NB = (N + 255) / 256;
    const int EB = (E + 255) / 256;
    const int AGGB = (N * WAVE + 255) / 256;
    const int GB = (N + 127) / 128;  // gemm tile blocks

    // CSR build + dinv
    hipMemsetAsync(cnt, 0, (size_t)N * 4, stream);
    k_count<<<EB, 256, 0, stream>>>(dstE, cnt, E);
    k_dinv<<<NB, 256, 0, stream>>>(cnt, dinv, N);
    k_scan1<<<NB, 256, 0, stream>>>(cnt, rstart, bsum, N);
    k_scan2<<<1, 512, 0, stream>>>(bsum, NB);
    k_scan3<<<NB, 256, 0, stream>>>(rstart, bsum, cursor, N);
    k_fill<<<EB, 256, 0, stream>>>(srcE, dstE, cursor, ssorted, E);

    // Layer 1: 256 -> 128, relu
    gemm_tile<256, 128, 16, 16, 8, 8><<<GB, 256, 0, stream>>>(x, W1, dinv, bufS, N);
    agg128<true><<<AGGB, 256, 0, stream>>>(bufS, ssorted, rstart, cnt, dinv, b1, bufH, N);
    // Layer 2: 128 -> 128, relu
    gemm_tile<128, 128, 16, 16, 8, 8><<<GB, 256, 0, stream>>>(bufH, W2, dinv, bufS, N);
    agg128<true><<<AGGB, 256, 0, stream>>>(bufS, ssorted, rstart, cnt, dinv, b2, bufH, N);
    // Layer 3: 128 -> 40, no relu
    gemm_tile<128, 40, 8, 32, 4, 5><<<GB, 256, 0, stream>>>(bufH, W3, dinv, bufS, N);
    agg40<<<AGGB, 256, 0, stream>>>(bufS, ssorted, rstart, cnt, dinv, b3, out, N);
}